// Round 11
// baseline (187.022 us; speedup 1.0000x reference)
//
#include <hip/hip_runtime.h>
#include <hip/hip_bf16.h>
#include <math.h>

#define B_ 2
#define T_ 2048
#define D_ 1024
#define H_ 16
#define HD 64

typedef __bf16 bf16;
typedef bf16 bf16x8 __attribute__((ext_vector_type(8)));
typedef bf16 bf16x4 __attribute__((ext_vector_type(4)));
typedef short short4v __attribute__((ext_vector_type(4)));
typedef float f32x4 __attribute__((ext_vector_type(4)));

// async global->LDS, 16B per lane. LDS dest must be wave-uniform base + lane*16 (m104/m108).
#define GL2LDS16(g, l) __builtin_amdgcn_global_load_lds(                      \
    (const __attribute__((address_space(1))) void*)(g),                       \
    (__attribute__((address_space(3))) void*)(l), 16, 0, 0)

// 16x16x16 bf16 MFMA (K=16): gfx90a-era builtin name; guarded from the host pass.
static __device__ __forceinline__ f32x4 mfma16x16x16(bf16x4 a, bf16x4 b, f32x4 c) {
#if defined(__HIP_DEVICE_COMPILE__)
# if __has_builtin(__builtin_amdgcn_mfma_f32_16x16x16bf16_1k)
    return __builtin_amdgcn_mfma_f32_16x16x16bf16_1k(
        __builtin_bit_cast(short4v, a), __builtin_bit_cast(short4v, b), c, 0, 0, 0);
# else
    asm("v_mfma_f32_16x16x16_bf16 %0, %1, %2, %0" : "+v"(c) : "v"(a), "v"(b));
    return c;
# endif
#else
    (void)a; (void)b;
    return c;
#endif
}

static __device__ __forceinline__ bf16x4 lo4(bf16x8 v) {
    return __builtin_shufflevector(v, v, 0, 1, 2, 3);
}
static __device__ __forceinline__ bf16x4 hi4(bf16x8 v) {
    return __builtin_shufflevector(v, v, 4, 5, 6, 7);
}

// ------------------- fused prep: z 0..3 = transpose W_z -> bf16 [n][k]; z 4..19 = cast x
__global__ __launch_bounds__(256) void prep_inputs(const float* __restrict__ x,
                                                   const float* __restrict__ W0,
                                                   const float* __restrict__ W1,
                                                   const float* __restrict__ W2,
                                                   const float* __restrict__ W3,
                                                   bf16* __restrict__ xb,
                                                   bf16* __restrict__ Wt) {
    const int z = blockIdx.z;
    const int tid = threadIdx.x;
    if (z >= 4) {
        size_t i = ((((size_t)(z - 4) * 256 + blockIdx.y * 16 + blockIdx.x) * 256) + tid) * 4;
        float4 v = *(const float4*)(x + i);
        bf16 tmp[4] = {(bf16)v.x, (bf16)v.y, (bf16)v.z, (bf16)v.w};
        *(uint2*)(xb + i) = *(const uint2*)tmp;
        return;
    }
    __shared__ bf16 tile[64 * 72];
    const float* W = (z == 0) ? W0 : (z == 1) ? W1 : (z == 2) ? W2 : W3;
    bf16* out = Wt + (size_t)z * D_ * D_;
    const int k0 = blockIdx.y * 64, n0 = blockIdx.x * 64;
    for (int it = 0; it < 4; ++it) {
        int idx = it * 256 + tid;
        int r = idx >> 4;                // k row
        int c4 = (idx & 15) << 2;        // n col
        float4 v = *(const float4*)(W + (size_t)(k0 + r) * D_ + n0 + c4);
        tile[(c4 + 0) * 72 + r] = (bf16)v.x;
        tile[(c4 + 1) * 72 + r] = (bf16)v.y;
        tile[(c4 + 2) * 72 + r] = (bf16)v.z;
        tile[(c4 + 3) * 72 + r] = (bf16)v.w;
    }
    __syncthreads();
    for (int it = 0; it < 2; ++it) {
        int idx = it * 256 + tid;
        int r = idx >> 3;                // n row
        int c8 = (idx & 7) << 3;         // k col
        bf16x8 v = *(const bf16x8*)&tile[r * 72 + c8];
        *(bf16x8*)(out + (size_t)(n0 + r) * D_ + k0 + c8) = v;
    }
}

// ---------------------------------------------------------------- z-fused QKV GEMM, BM=64
// Round-11: BM=64, BN=64, BK=64, 256 threads (4 waves 2x2, wave-tile 32x32),
// acc[3][2][2], single-buffered LDS 32 KB -> grid 1024 = 4 resident blocks/CU
// (was 512 blocks = 2/CU). Rationale: round-2 direct PMC showed the GEMM is
// ~85% stall at the per-K-step vmcnt(0) drain; in-block pipelining is null
// (round 6, m97 structural stall) but cross-block wave overlap (m114) scales
// with resident blocks. Trade: MFMA:load 4.8->3, B L2-traffic 2x (headroom 10x).
// 1-D XCD-grouped grid: xcd=bid&7 owns y-panels [8*xcd,8*xcd+8) (1 MB A, L2-res).
// z=0(Q),1(K) -> [B,H,T,hd] (swapped MFMA: r->d); z=2(V) -> [B,H,hd,T] (unswapped)
__global__ __launch_bounds__(256) void gemm_qkv(const bf16* __restrict__ A,
                                                const bf16* __restrict__ Bt,
                                                bf16* __restrict__ Cout) {
    __shared__ bf16 As[2][64 * 32];         // [k-half][row*32 + col] linear
    __shared__ bf16 Bs[3][2][64 * 32];      // [z][k-half][...]
    const int bid = blockIdx.x;              // 0..1023, bijective remap
    const int xcd = bid & 7, rr = bid >> 3;  // rr 0..127
    const int y   = (xcd << 3) + (rr & 7);   // 0..63 (M tile)
    const int xx  = rr >> 3;                 // 0..15 (N tile)
    const int m0 = y * 64, n0 = xx * 64;

    const int tid = threadIdx.x;
    const int wave = tid >> 6, lane = tid & 63;
    const int quad = lane >> 4, l16 = lane & 15;
    const int wr = wave >> 1, wc = wave & 1;

    const int lrow = tid >> 2, lcol8 = (tid & 3) << 3;   // 256 thr cover one 64x32 half
    const bf16* ag = A + (size_t)(m0 + lrow) * D_ + lcol8;
    const size_t brow = (size_t)(n0 + lrow) * D_ + lcol8;
    const int soff = lrow * 32 + lcol8;      // = tid*16B linear (GL2LDS dest rule)

    f32x4 acc[3][2][2];
#pragma unroll
    for (int z = 0; z < 3; ++z)
#pragma unroll
        for (int mi = 0; mi < 2; ++mi)
#pragma unroll
            for (int ni = 0; ni < 2; ++ni) acc[z][mi][ni] = (f32x4){0.f, 0.f, 0.f, 0.f};

    for (int kb = 0; kb < D_; kb += 64) {
        GL2LDS16(ag + kb,      &As[0][soff]);
        GL2LDS16(ag + kb + 32, &As[1][soff]);
#pragma unroll
        for (int z = 0; z < 3; ++z) {
            const bf16* bg = Bt + (size_t)z * D_ * D_ + brow;
            GL2LDS16(bg + kb,      &Bs[z][0][soff]);
            GL2LDS16(bg + kb + 32, &Bs[z][1][soff]);
        }
        __syncthreads();   // drains vmcnt -> LDS writes visible

#pragma unroll
        for (int half = 0; half < 2; ++half) {
            bf16x8 af[2];
#pragma unroll
            for (int mi = 0; mi < 2; ++mi)
                af[mi] = *(const bf16x8*)&As[half][(wr * 32 + mi * 16 + l16) * 32 + quad * 8];
#pragma unroll
            for (int z = 0; z < 3; ++z) {
                bf16x8 bfr[2];
#pragma unroll
                for (int ni = 0; ni < 2; ++ni)
                    bfr[ni] = *(const bf16x8*)&Bs[z][half][(wc * 32 + ni * 16 + l16) * 32 + quad * 8];
                if (z < 2) {
#pragma unroll
                    for (int mi = 0; mi < 2; ++mi)
#pragma unroll
                        for (int ni = 0; ni < 2; ++ni)
                            acc[z][mi][ni] = __builtin_amdgcn_mfma_f32_16x16x32_bf16(
                                bfr[ni], af[mi], acc[z][mi][ni], 0, 0, 0);
                } else {
#pragma unroll
                    for (int mi = 0; mi < 2; ++mi)
#pragma unroll
                        for (int ni = 0; ni < 2; ++ni)
                            acc[z][mi][ni] = __builtin_amdgcn_mfma_f32_16x16x32_bf16(
                                af[mi], bfr[ni], acc[z][mi][ni], 0, 0, 0);
                }
            }
        }
        __syncthreads();
    }

#pragma unroll
    for (int z = 0; z < 3; ++z) {
        bf16* Cb = Cout + (size_t)z * (B_ * T_) * D_;
        const float qscale = (z == 0) ? 0.180336887f : 1.0f;  // 0.125*log2(e) folded into Q
        if (z < 2) {
#pragma unroll
            for (int mi = 0; mi < 2; ++mi)
#pragma unroll
                for (int ni = 0; ni < 2; ++ni) {
                    int m = m0 + wr * 32 + mi * 16 + l16;
                    int n = n0 + wc * 32 + ni * 16 + quad * 4;
                    int b = m >> 11, t = m & (T_ - 1);
                    int h = n >> 6, d = n & (HD - 1);
                    bf16 o4[4];
                    for (int r = 0; r < 4; ++r) o4[r] = (bf16)(acc[z][mi][ni][r] * qscale);
                    *(uint2*)&Cb[(((((size_t)b * H_ + h) * T_ + t) << 6) + d)] =
                        *(const uint2*)o4;
                }
        } else {
#pragma unroll
            for (int mi = 0; mi < 2; ++mi)
#pragma unroll
                for (int ni = 0; ni < 2; ++ni) {
                    int m = m0 + wr * 32 + mi * 16 + quad * 4;
                    int n = n0 + wc * 32 + ni * 16 + l16;
                    int b = m >> 11, t = m & (T_ - 1);
                    int h = n >> 6, d = n & (HD - 1);
                    bf16 o4[4];
                    for (int r = 0; r < 4; ++r) o4[r] = (bf16)acc[z][mi][ni][r];
                    *(uint2*)&Cb[((((size_t)b * H_ + h) * HD + d) * T_ + t)] =
                        *(const uint2*)o4;
                }
        }
    }
}

// ---------------------------------------------------------------- out-proj GEMM, 2-phase dbuf
// (round-6/7/10 verbatim)
__global__ __launch_bounds__(256) void gemm_out(const bf16* __restrict__ A,
                                                const bf16* __restrict__ Bt,
                                                float* __restrict__ Cout) {
    __shared__ bf16 As[2][2][128 * 32];
    __shared__ bf16 Bs[2][2][64 * 32];
    const int bid = blockIdx.x;              // 0..511, bijective remap
    const int xcd = bid & 7, rr = bid >> 3;  // rr 0..63
    const int y   = (xcd << 2) + (rr & 3);   // 0..31 (M tile)
    const int xx  = rr >> 2;                 // 0..15 (N tile)
    const int m0 = y * 128, n0 = xx * 64;

    const int tid = threadIdx.x;
    const int wave = tid >> 6, lane = tid & 63;
    const int quad = lane >> 4, l16 = lane & 15;
    const int wr = wave >> 1, wc = wave & 1;

    const int lrow = lane >> 2, lcol = (lane & 3) << 3;
    const bf16* ag = A  + (size_t)(m0 + wave * 32 + lrow) * D_ + lcol;
    const bf16* bg = Bt + (size_t)(n0 + wave * 16 + lrow) * D_ + lcol;
    const int a_off = (wave * 32 + lrow) * 32 + lcol;
    const int b_off = (wave * 16 + lrow) * 32 + lcol;

    f32x4 acc[4][2];
    for (int mi = 0; mi < 4; ++mi)
        for (int ni = 0; ni < 2; ++ni) acc[mi][ni] = (f32x4){0.f, 0.f, 0.f, 0.f};

    auto stage = [&](int buf, int kb) {
        GL2LDS16(ag + kb,                        &As[buf][0][a_off]);
        GL2LDS16(ag + (size_t)16 * D_ + kb,      &As[buf][0][a_off + 16 * 32]);
        GL2LDS16(ag + kb + 32,                   &As[buf][1][a_off]);
        GL2LDS16(ag + (size_t)16 * D_ + kb + 32, &As[buf][1][a_off + 16 * 32]);
        GL2LDS16(bg + kb,                        &Bs[buf][0][b_off]);
        GL2LDS16(bg + kb + 32,                   &Bs[buf][1][b_off]);
    };

    stage(0, 0);
    __syncthreads();
    int cur = 0;
    for (int kb = 0; kb < D_; kb += 64) {
        if (kb + 64 < D_) stage(cur ^ 1, kb + 64);
#pragma unroll
        for (int half = 0; half < 2; ++half) {
            bf16x8 af[4], bfr[2];
#pragma unroll
            for (int mi = 0; mi < 4; ++mi)
                af[mi] = *(const bf16x8*)&As[cur][half][(wr * 64 + mi * 16 + l16) * 32 + quad * 8];
#pragma unroll
            for (int ni = 0; ni < 2; ++ni)
                bfr[ni] = *(const bf16x8*)&Bs[cur][half][(wc * 32 + ni * 16 + l16) * 32 + quad * 8];
#pragma unroll
            for (int mi = 0; mi < 4; ++mi)
#pragma unroll
                for (int ni = 0; ni < 2; ++ni)
                    acc[mi][ni] = __builtin_amdgcn_mfma_f32_16x16x32_bf16(
                        bfr[ni], af[mi], acc[mi][ni], 0, 0, 0);
        }
        __syncthreads();
        cur ^= 1;
    }

    for (int mi = 0; mi < 4; ++mi)
        for (int ni = 0; ni < 2; ++ni) {
            int m = m0 + wr * 64 + mi * 16 + l16;
            int n = n0 + wc * 32 + ni * 16 + quad * 4;
            *(f32x4*)&Cout[(size_t)m * D_ + n] = acc[mi][ni];
        }
}

// ---------------------------------------------------------------- flash attention
// (round-10 verbatim: round-7 structure + v_max3 trees)
__device__ __constant__ unsigned char ITEM_QT[24] = {
    8,9,10,11,12,13,14,15, 7,15, 6,14, 5,13, 4,12, 3,11, 2,10, 1,9, 0,8};
__device__ __constant__ unsigned char ITEM_KIND[24] = {  // 0=full 1=chunk0 2=chunk1
    1,1,1,1,1,1,1,1, 0,2, 0,2, 0,2, 0,2, 0,2, 0,2, 0,2, 0,2};

#define LDP 136

struct VStage { bf16x8 v0, v1; };

__global__ __launch_bounds__(512, 4) void attn_kernel(const bf16* __restrict__ Q,
                                                      const bf16* __restrict__ K,
                                                      const bf16* __restrict__ Vt,
                                                      bf16* __restrict__ O,
                                                      float* __restrict__ Opart,
                                                      float2* __restrict__ ML) {
    __shared__ bf16 Kh[2][2][128 * 32];  // [buf][k-half][key*32 + kcol] linear
    __shared__ bf16 Vs[64 * LDP];        // [dim][permuted key col]

    const int bh = blockIdx.x;                 // 0..31
    const int item = blockIdx.y;               // 0..23 (descending size)
    const int qt = ITEM_QT[item];              // 128-row q tile
    const int kind = ITEM_KIND[item];
    const int h = bh & (H_ - 1), b = bh >> 4;
    const int tid = threadIdx.x;
    const int wave = tid >> 6, lane = tid & 63;
    const int quad = lane >> 4, l16 = lane & 15;

    const bf16* Qb = Q + (size_t)bh * T_ * HD;
    const bf16* Kb = K + (size_t)bh * T_ * HD;
    const bf16* Vb = Vt + (size_t)bh * HD * T_;   // [hd][T]

    const float slope2 = exp2f(-0.5f * (float)(h + 1)) * 1.44269504f;  // log2-domain slope

    bf16x8 qf[2];
    {
        const bf16* qrow = Qb + (size_t)(qt * 128 + wave * 16 + l16) * HD + quad * 8;
        qf[0] = *(const bf16x8*)(qrow);
        qf[1] = *(const bf16x8*)(qrow + 32);
    }

    // K staging via gl2lds: thread t covers key = t>>2, kcol = (t&3)*8 of each half.
    auto stageK = [&](int buf, int t) {
        const bf16* kg = Kb + ((size_t)t * 128 + (tid >> 2)) * HD + ((tid & 3) << 3);
        GL2LDS16(kg,      &Kh[buf][0][tid * 8]);
        GL2LDS16(kg + 32, &Kh[buf][1][tid * 8]);
    };

    // V staging (reg round-trip for the permuted-column layout)
    const int slot0 = tid, slot1 = 512 + tid;
    const int rv0 = slot0 >> 4, c0 = slot0 & 15;
    const int rv1 = slot1 >> 4, c1 = slot1 & 15;
    const int vs0 = rv0 * LDP + (c0 & 1) * 64 + (c0 >> 1) * 4;
    const int vs1 = rv1 * LDP + (c1 & 1) * 64 + (c1 >> 1) * 4;

    auto loadV = [&](int t, VStage& st) {
        const bf16* vb = Vb + t * 128;
        st.v0 = *(const bf16x8*)(vb + (size_t)rv0 * T_ + c0 * 8);
        st.v1 = *(const bf16x8*)(vb + (size_t)rv1 * T_ + c1 * 8);
    };
    auto storeV = [&](const VStage& st) {
        *(bf16x4*)&Vs[vs0]      = lo4(st.v0);
        *(bf16x4*)&Vs[vs0 + 32] = hi4(st.v0);
        *(bf16x4*)&Vs[vs1]      = lo4(st.v1);
        *(bf16x4*)&Vs[vs1 + 32] = hi4(st.v1);
    };

    f32x4 acc[4];                    // O^T: d = df*16+quad*4+r, query = l16
    for (int df = 0; df < 4; ++df) acc[df] = (f32x4){0.f, 0.f, 0.f, 0.f};
    float m_run = -INFINITY, l_lane = 0.f;

    const int qglob = qt * 128 + wave * 16 + l16;
    const int nkt = qt + 1;                        // 128-key tiles for full row
    const int kt0 = (kind == 2) ? 8 : 0;
    const int kt1 = (kind == 1) ? 8 : nkt;

    auto compute = [&](int kt, int buf, bool last) {
        f32x4 s[8];
#pragma unroll
        for (int nf = 0; nf < 8; ++nf) {
            bf16x8 kf0 = *(const bf16x8*)&Kh[buf][0][(nf * 16 + l16) * 32 + quad * 8];
            bf16x8 kf1 = *(const bf16x8*)&Kh[buf][1][(nf * 16 + l16) * 32 + quad * 8];
            f32x4 zz = (f32x4){0.f, 0.f, 0.f, 0.f};
            __builtin_amdgcn_s_setprio(1);
            zz = __builtin_amdgcn_mfma_f32_16x16x32_bf16(kf0, qf[0], zz, 0, 0, 0);
            zz = __builtin_amdgcn_mfma_f32_16x16x32_bf16(kf1, qf[1], zz, 0, 0, 0);
            __builtin_amdgcn_s_setprio(0);
            s[nf] = zz;
        }

        // Q pre-scaled -> s already in log2 domain; add alibi, mask last tile
        const float j0f = (float)(kt * 128 + quad * 4 - (T_ - 1));
#pragma unroll
        for (int nf = 0; nf < 8; ++nf)
#pragma unroll
            for (int r = 0; r < 4; ++r)
                s[nf][r] += slope2 * (j0f + (float)(nf * 16 + r));
        if (last) {
            const int jb = kt * 128 + quad * 4;
#pragma unroll
            for (int nf = 0; nf < 8; ++nf)
#pragma unroll
                for (int r = 0; r < 4; ++r)
                    if (jb + nf * 16 + r > qglob) s[nf][r] = -INFINITY;
        }

        // max reduction, v_max3-fusable nesting (T17), then cross-quad
        float a[8];
#pragma unroll
        for (int nf = 0; nf < 8; ++nf)
            a[nf] = fmaxf(fmaxf(fmaxf(s[nf][0], s[nf][1]), s[nf][2]), s[nf][3]);
        float m012 = fmaxf(fmaxf(a[0], a[1]), a[2]);
        float m345 = fmaxf(fmaxf(a[3], a[4]), a[5]);
        float m67  = fmaxf(a[6], a[7]);
        float mx = fmaxf(fmaxf(m012, m345), m67);
        mx = fmaxf(mx, __shfl_xor(mx, 16, 64));
        mx = fmaxf(mx, __shfl_xor(mx, 32, 64));

        // defer-max (T13): rescale only when tile max grew past threshold (log2 domain)
        if (!__all(mx - m_run <= 8.f)) {
            const float mnew = fmaxf(m_run, mx);
            const float alpha = exp2f(m_run - mnew);
            l_lane *= alpha;
#pragma unroll
            for (int df = 0; df < 4; ++df) acc[df] *= alpha;
            m_run = mnew;
        }

        float rs0 = 0.f, rs1 = 0.f;
        bf16x4 pf[8];
#pragma unroll
        for (int nf = 0; nf < 8; ++nf) {
            float p0 = exp2f(s[nf][0] - m_run);
            float p1 = exp2f(s[nf][1] - m_run);
            float p2 = exp2f(s[nf][2] - m_run);
            float p3 = exp2f(s[nf][3] - m_run);
            if (nf & 1) rs1 += (p0 + p1) + (p2 + p3);
            else        rs0 += (p0 + p1) + (p2 + p3);
            pf[nf] = (bf16x4){(bf16)p0, (bf16)p1, (bf16)p2, (bf16)p3};
        }
        l_lane += rs0 + rs1;          // cross-quad l reduction deferred to epilogue

        // PV: permuted V cols -> b128 reads (2-way on writes only = free)
#pragma unroll
        for (int j = 0; j < 4; ++j) {
            bf16x8 w[4];
#pragma unroll
            for (int df = 0; df < 4; ++df)
                w[df] = *(const bf16x8*)&Vs[(df * 16 + l16) * LDP + quad * 32 + j * 8];
            __builtin_amdgcn_s_setprio(1);
#pragma unroll
            for (int df = 0; df < 4; ++df) {
                acc[df] = mfma16x16x16(lo4(w[df]), pf[2 * j],     acc[df]);
                acc[df] = mfma16x16x16(hi4(w[df]), pf[2 * j + 1], acc[df]);
            }
            __builtin_amdgcn_s_setprio(0);
        }
    };

    // Pipeline: K double-buffered in LDS (gl2lds), V single-buffered with reg prefetch.
    // Prefetches for kt+1 issued AFTER barrier (B), drained at the NEXT (B).
    VStage sA, sB;
    stageK(0, kt0);
    loadV(kt0, sA);
    int kt = kt0;
    for (;;) {
        __syncthreads();               // (A) prior compute's Vs reads done
        storeV(sA);                    // waits on V(kt) regs (covered by prior compute)
        __syncthreads();               // (B) drains K(kt) gl2lds; V writes visible
        if (kt + 1 < kt1) { stageK(1, kt + 1); loadV(kt + 1, sB); }
        compute(kt, 0, kt == nkt - 1);
        if (++kt >= kt1) break;
        __syncthreads();
        storeV(sB);
        __syncthreads();
        if (kt + 1 < kt1) { stageK(0, kt + 1); loadV(kt + 1, sA); }
        compute(kt, 1, kt == nkt - 1);
        if (++kt >= kt1) break;
    }

    float l_run = l_lane;
    l_run += __shfl_xor(l_run, 16, 64);
    l_run += __shfl_xor(l_run, 32, 64);

    if (kind == 0) {
        const float inv = 1.0f / l_run;
        for (int df = 0; df < 4; ++df) {
            bf16 o4[4];
            for (int r = 0; r < 4; ++r) o4[r] = (bf16)(acc[df][r] * inv);
            *(uint2*)&O[(((size_t)b * T_ + qglob) * H_ + h) * HD + df * 16 + quad * 4] =
                *(const uint2*)o4;
        }
    } else {
        const int pidx = (bh * 8 + (qt - 8)) * 2 + (kind == 2 ? 1 : 0);
        const int ql = wave * 16 + l16;        // 0..127
        float* dst = Opart + (size_t)pidx * 8192 + ql * 64;
        for (int df = 0; df < 4; ++df)
            *(f32x4*)&dst[df * 16 + quad * 4] = acc[df];
        if (quad == 0) ML[pidx * 128 + ql] = make_float2(m_run, l_run);
    }
}

// ---------------------------------------------------------------- partial merge
// grid (8, 32) x 512 thr: q = tid>>2 (0..127), d-chunk = (tid&3)*16.
__global__ __launch_bounds__(512) void attn_merge(const float* __restrict__ Opart,
                                                  const float2* __restrict__ ML,
                                                  bf16* __restrict__ O) {
    const int qt = 8 + blockIdx.x, bh = blockIdx.y;
    const int h = bh & (H_ - 1), b = bh >> 4;
    const int tid = threadIdx.x;
    const int q = tid >> 2, dc = (tid & 3) << 4;
    const int p0 = (bh * 8 + blockIdx.x) * 2, p1 = p0 + 1;

    const float2 ml0 = ML[p0 * 128 + q], ml1 = ML[p1 * 128 + q];
    const float M = fmaxf(ml0.x, ml1.x);
    const float e0 = exp2f(ml0.x - M), e1 = exp2f(ml1.x - M);
    const float inv = 1.0f / (e0 * ml0.y + e1 * ml1.y);

    const float* a = Opart + (size_t)p0 * 8192 + q * 64 + dc;
    const float* c = Opart + (size_t)p1 * 8192 + q * 64 + dc;
    bf16 o16[16];
    for (int j = 0; j < 4; ++j) {
        f32x4 va = *(const f32x4*)(a + j * 4);
        f32x4 vc = *(const f32x4*)(c + j * 4);
        for (int r = 0; r < 4; ++r)
            o16[j * 4 + r] = (bf16)((va[r] * e0 + vc[r] * e1) * inv);
    }
    const int t = qt * 128 + q;
    bf16* dst = O + (((size_t)b * T_ + t) * H_ + h) * HD + dc;
    *(bf16x8*)dst = *(const bf16x8*)o16;
    *(bf16x8*)(dst + 8) = *(const bf16x8*)(o16 + 8);
}

// ---------------------------------------------------------------- launch
extern "C" void kernel_launch(void* const* d_in, const int* in_sizes, int n_in,
                              void* d_out, int out_size, void* d_ws, size_t ws_size,
                              hipStream_t stream) {
    const float* x  = (const float*)d_in[0];
    const float* Wq = (const float*)d_in[1];
    const float* Wk = (const float*)d_in[2];
    const float* Wv = (const float*)d_in[3];
    const float* Wo = (const float*)d_in[4];
    float* out = (float*)d_out;

    const size_t M = (size_t)B_ * T_;        // 4096
    const size_t XE = M * D_;                // 4 Mi elems
    const size_t WE = (size_t)D_ * D_;       // 1 Mi elems

    char* ws = (char*)d_ws;
    size_t off = 0;
    auto carve = [&](size_t bytes) {
        void* p = ws + off;
        off += (bytes + 255) & ~(size_t)255;
        return p;
    };
    bf16* xb  = (bf16*)carve(XE * 2);        // x bf16; reused as attn_out later
    bf16* Wt  = (bf16*)carve(4 * WE * 2);    // Wq,Wk,Wv,Wo transposed [N][K]
    bf16* QKV = (bf16*)carve(3 * XE * 2);    // Q,K [B,H,T,hd]; V [B,H,hd,T]
    float*  Opart = (float*)carve(32 * 8 * 2 * 8192 * sizeof(float));    // 16.8 MB
    float2* MLbuf = (float2*)carve(32 * 8 * 2 * 128 * sizeof(float2));   // 0.5 MB
    bf16* attn = xb;  // safe: xb fully consumed by QKV gemm before attn_kernel runs

    prep_inputs<<<dim3(16, 16, 20), 256, 0, stream>>>(x, Wq, Wk, Wv, Wo, xb, Wt);

    gemm_qkv<<<1024, 256, 0, stream>>>(xb, Wt, QKV);
    attn_kernel<<<dim3(32, 24), 512, 0, stream>>>(QKV, QKV + XE, QKV + 2 * XE,
                                                  attn, Opart, MLbuf);
    attn_merge<<<dim3(8, 32), 512, 0, stream>>>(Opart, MLbuf, attn);
    gemm_out<<<512, 256, 0, stream>>>(attn, Wt + 3 * WE, out);
}

// Round 12
// 182.367 us; speedup vs baseline: 1.0255x; 1.0255x over previous
//
#include <hip/hip_runtime.h>
#include <hip/hip_bf16.h>
#include <math.h>

#define B_ 2
#define T_ 2048
#define D_ 1024
#define H_ 16
#define HD 64

typedef __bf16 bf16;
typedef bf16 bf16x8 __attribute__((ext_vector_type(8)));
typedef bf16 bf16x4 __attribute__((ext_vector_type(4)));
typedef short short4v __attribute__((ext_vector_type(4)));
typedef float f32x4 __attribute__((ext_vector_type(4)));

// async global->LDS, 16B per lane. LDS dest must be wave-uniform base + lane*16 (m104/m108).
#define GL2LDS16(g, l) __builtin_amdgcn_global_load_lds(                      \
    (const __attribute__((address_space(1))) void*)(g),                       \
    (__attribute__((address_space(3))) void*)(l), 16, 0, 0)

// 16x16x16 bf16 MFMA (K=16): gfx90a-era builtin name; guarded from the host pass.
static __device__ __forceinline__ f32x4 mfma16x16x16(bf16x4 a, bf16x4 b, f32x4 c) {
#if defined(__HIP_DEVICE_COMPILE__)
# if __has_builtin(__builtin_amdgcn_mfma_f32_16x16x16bf16_1k)
    return __builtin_amdgcn_mfma_f32_16x16x16bf16_1k(
        __builtin_bit_cast(short4v, a), __builtin_bit_cast(short4v, b), c, 0, 0, 0);
# else
    asm("v_mfma_f32_16x16x16_bf16 %0, %1, %2, %0" : "+v"(c) : "v"(a), "v"(b));
    return c;
# endif
#else
    (void)a; (void)b;
    return c;
#endif
}

static __device__ __forceinline__ bf16x4 lo4(bf16x8 v) {
    return __builtin_shufflevector(v, v, 0, 1, 2, 3);
}
static __device__ __forceinline__ bf16x4 hi4(bf16x8 v) {
    return __builtin_shufflevector(v, v, 4, 5, 6, 7);
}

// ------------------- fused prep: z 0..3 = transpose W_z -> bf16 [n][k]; z 4..19 = cast x
__global__ __launch_bounds__(256) void prep_inputs(const float* __restrict__ x,
                                                   const float* __restrict__ W0,
                                                   const float* __restrict__ W1,
                                                   const float* __restrict__ W2,
                                                   const float* __restrict__ W3,
                                                   bf16* __restrict__ xb,
                                                   bf16* __restrict__ Wt) {
    const int z = blockIdx.z;
    const int tid = threadIdx.x;
    if (z >= 4) {
        size_t i = ((((size_t)(z - 4) * 256 + blockIdx.y * 16 + blockIdx.x) * 256) + tid) * 4;
        float4 v = *(const float4*)(x + i);
        bf16 tmp[4] = {(bf16)v.x, (bf16)v.y, (bf16)v.z, (bf16)v.w};
        *(uint2*)(xb + i) = *(const uint2*)tmp;
        return;
    }
    __shared__ bf16 tile[64 * 72];
    const float* W = (z == 0) ? W0 : (z == 1) ? W1 : (z == 2) ? W2 : W3;
    bf16* out = Wt + (size_t)z * D_ * D_;
    const int k0 = blockIdx.y * 64, n0 = blockIdx.x * 64;
    for (int it = 0; it < 4; ++it) {
        int idx = it * 256 + tid;
        int r = idx >> 4;                // k row
        int c4 = (idx & 15) << 2;        // n col
        float4 v = *(const float4*)(W + (size_t)(k0 + r) * D_ + n0 + c4);
        tile[(c4 + 0) * 72 + r] = (bf16)v.x;
        tile[(c4 + 1) * 72 + r] = (bf16)v.y;
        tile[(c4 + 2) * 72 + r] = (bf16)v.z;
        tile[(c4 + 3) * 72 + r] = (bf16)v.w;
    }
    __syncthreads();
    for (int it = 0; it < 2; ++it) {
        int idx = it * 256 + tid;
        int r = idx >> 3;                // n row
        int c8 = (idx & 7) << 3;         // k col
        bf16x8 v = *(const bf16x8*)&tile[r * 72 + c8];
        *(bf16x8*)(out + (size_t)(n0 + r) * D_ + k0 + c8) = v;
    }
}

// ---------------------------------------------------------------- z-fused QKV GEMM, 2-phase dbuf
// (round-6/7/10 verbatim — best verified: BM=128, BN=64, 256 thr, acc[3][4][2])
__global__ __launch_bounds__(256) void gemm_qkv(const bf16* __restrict__ A,
                                                const bf16* __restrict__ Bt,
                                                bf16* __restrict__ Cout) {
    __shared__ bf16 As[2][2][128 * 32];     // [buf][k-half][...]
    __shared__ bf16 Bs[2][3][2][64 * 32];   // [buf][z][k-half][...]
    const int bid = blockIdx.x;              // 0..511, bijective remap
    const int xcd = bid & 7, rr = bid >> 3;  // rr 0..63
    const int y   = (xcd << 2) + (rr & 3);   // 0..31 (M tile)
    const int xx  = rr >> 2;                 // 0..15 (N tile)
    const int m0 = y * 128, n0 = xx * 64;

    const int tid = threadIdx.x;
    const int wave = tid >> 6, lane = tid & 63;
    const int quad = lane >> 4, l16 = lane & 15;
    const int wr = wave >> 1, wc = wave & 1;

    const int lrow = lane >> 2, lcol = (lane & 3) << 3;
    const bf16* ag = A + (size_t)(m0 + wave * 32 + lrow) * D_ + lcol;
    const size_t brow = (size_t)(n0 + wave * 16 + lrow) * D_ + lcol;
    const int a_off = (wave * 32 + lrow) * 32 + lcol;
    const int b_off = (wave * 16 + lrow) * 32 + lcol;

    f32x4 acc[3][4][2];
#pragma unroll
    for (int z = 0; z < 3; ++z)
#pragma unroll
        for (int mi = 0; mi < 4; ++mi)
#pragma unroll
            for (int ni = 0; ni < 2; ++ni) acc[z][mi][ni] = (f32x4){0.f, 0.f, 0.f, 0.f};

    auto stage = [&](int buf, int kb) {
        GL2LDS16(ag + kb,                        &As[buf][0][a_off]);
        GL2LDS16(ag + (size_t)16 * D_ + kb,      &As[buf][0][a_off + 16 * 32]);
        GL2LDS16(ag + kb + 32,                   &As[buf][1][a_off]);
        GL2LDS16(ag + (size_t)16 * D_ + kb + 32, &As[buf][1][a_off + 16 * 32]);
#pragma unroll
        for (int z = 0; z < 3; ++z) {
            const bf16* bg = Bt + (size_t)z * D_ * D_ + brow;
            GL2LDS16(bg + kb,      &Bs[buf][z][0][b_off]);
            GL2LDS16(bg + kb + 32, &Bs[buf][z][1][b_off]);
        }
    };

    stage(0, 0);
    __syncthreads();               // prologue drain
    int cur = 0;
    for (int kb = 0; kb < D_; kb += 64) {
        if (kb + 64 < D_) stage(cur ^ 1, kb + 64);   // issue next tile FIRST
#pragma unroll
        for (int half = 0; half < 2; ++half) {
            bf16x8 af[4];
#pragma unroll
            for (int mi = 0; mi < 4; ++mi)
                af[mi] = *(const bf16x8*)&As[cur][half][(wr * 64 + mi * 16 + l16) * 32 + quad * 8];
#pragma unroll
            for (int z = 0; z < 3; ++z) {
                bf16x8 bfr[2];
#pragma unroll
                for (int ni = 0; ni < 2; ++ni)
                    bfr[ni] = *(const bf16x8*)&Bs[cur][z][half][(wc * 32 + ni * 16 + l16) * 32 + quad * 8];
                if (z < 2) {
#pragma unroll
                    for (int mi = 0; mi < 4; ++mi)
#pragma unroll
                        for (int ni = 0; ni < 2; ++ni)
                            acc[z][mi][ni] = __builtin_amdgcn_mfma_f32_16x16x32_bf16(
                                bfr[ni], af[mi], acc[z][mi][ni], 0, 0, 0);
                } else {
#pragma unroll
                    for (int mi = 0; mi < 4; ++mi)
#pragma unroll
                        for (int ni = 0; ni < 2; ++ni)
                            acc[z][mi][ni] = __builtin_amdgcn_mfma_f32_16x16x32_bf16(
                                af[mi], bfr[ni], acc[z][mi][ni], 0, 0, 0);
                }
            }
        }
        __syncthreads();           // one drain per K-step, AFTER compute
        cur ^= 1;
    }

#pragma unroll
    for (int z = 0; z < 3; ++z) {
        bf16* Cb = Cout + (size_t)z * (B_ * T_) * D_;
        const float qscale = (z == 0) ? 0.180336887f : 1.0f;  // 0.125*log2(e) folded into Q
        if (z < 2) {
#pragma unroll
            for (int mi = 0; mi < 4; ++mi)
#pragma unroll
                for (int ni = 0; ni < 2; ++ni) {
                    int m = m0 + wr * 64 + mi * 16 + l16;
                    int n = n0 + wc * 32 + ni * 16 + quad * 4;
                    int b = m >> 11, t = m & (T_ - 1);
                    int h = n >> 6, d = n & (HD - 1);
                    bf16 o4[4];
                    for (int r = 0; r < 4; ++r) o4[r] = (bf16)(acc[z][mi][ni][r] * qscale);
                    *(uint2*)&Cb[(((((size_t)b * H_ + h) * T_ + t) << 6) + d)] =
                        *(const uint2*)o4;
                }
        } else {
#pragma unroll
            for (int mi = 0; mi < 4; ++mi)
#pragma unroll
                for (int ni = 0; ni < 2; ++ni) {
                    int m = m0 + wr * 64 + mi * 16 + quad * 4;
                    int n = n0 + wc * 32 + ni * 16 + l16;
                    int b = m >> 11, t = m & (T_ - 1);
                    int h = n >> 6, d = n & (HD - 1);
                    bf16 o4[4];
                    for (int r = 0; r < 4; ++r) o4[r] = (bf16)acc[z][mi][ni][r];
                    *(uint2*)&Cb[((((size_t)b * H_ + h) * HD + d) * T_ + t)] =
                        *(const uint2*)o4;
                }
        }
    }
}

// ---------------------------------------------------------------- out-proj GEMM, 2-phase dbuf
// (round-6/7/10 verbatim)
__global__ __launch_bounds__(256) void gemm_out(const bf16* __restrict__ A,
                                                const bf16* __restrict__ Bt,
                                                float* __restrict__ Cout) {
    __shared__ bf16 As[2][2][128 * 32];
    __shared__ bf16 Bs[2][2][64 * 32];
    const int bid = blockIdx.x;              // 0..511, bijective remap
    const int xcd = bid & 7, rr = bid >> 3;  // rr 0..63
    const int y   = (xcd << 2) + (rr & 3);   // 0..31 (M tile)
    const int xx  = rr >> 2;                 // 0..15 (N tile)
    const int m0 = y * 128, n0 = xx * 64;

    const int tid = threadIdx.x;
    const int wave = tid >> 6, lane = tid & 63;
    const int quad = lane >> 4, l16 = lane & 15;
    const int wr = wave >> 1, wc = wave & 1;

    const int lrow = lane >> 2, lcol = (lane & 3) << 3;
    const bf16* ag = A  + (size_t)(m0 + wave * 32 + lrow) * D_ + lcol;
    const bf16* bg = Bt + (size_t)(n0 + wave * 16 + lrow) * D_ + lcol;
    const int a_off = (wave * 32 + lrow) * 32 + lcol;
    const int b_off = (wave * 16 + lrow) * 32 + lcol;

    f32x4 acc[4][2];
    for (int mi = 0; mi < 4; ++mi)
        for (int ni = 0; ni < 2; ++ni) acc[mi][ni] = (f32x4){0.f, 0.f, 0.f, 0.f};

    auto stage = [&](int buf, int kb) {
        GL2LDS16(ag + kb,                        &As[buf][0][a_off]);
        GL2LDS16(ag + (size_t)16 * D_ + kb,      &As[buf][0][a_off + 16 * 32]);
        GL2LDS16(ag + kb + 32,                   &As[buf][1][a_off]);
        GL2LDS16(ag + (size_t)16 * D_ + kb + 32, &As[buf][1][a_off + 16 * 32]);
        GL2LDS16(bg + kb,                        &Bs[buf][0][b_off]);
        GL2LDS16(bg + kb + 32,                   &Bs[buf][1][b_off]);
    };

    stage(0, 0);
    __syncthreads();
    int cur = 0;
    for (int kb = 0; kb < D_; kb += 64) {
        if (kb + 64 < D_) stage(cur ^ 1, kb + 64);
#pragma unroll
        for (int half = 0; half < 2; ++half) {
            bf16x8 af[4], bfr[2];
#pragma unroll
            for (int mi = 0; mi < 4; ++mi)
                af[mi] = *(const bf16x8*)&As[cur][half][(wr * 64 + mi * 16 + l16) * 32 + quad * 8];
#pragma unroll
            for (int ni = 0; ni < 2; ++ni)
                bfr[ni] = *(const bf16x8*)&Bs[cur][half][(wc * 32 + ni * 16 + l16) * 32 + quad * 8];
#pragma unroll
            for (int mi = 0; mi < 4; ++mi)
#pragma unroll
                for (int ni = 0; ni < 2; ++ni)
                    acc[mi][ni] = __builtin_amdgcn_mfma_f32_16x16x32_bf16(
                        bfr[ni], af[mi], acc[mi][ni], 0, 0, 0);
        }
        __syncthreads();
        cur ^= 1;
    }

    for (int mi = 0; mi < 4; ++mi)
        for (int ni = 0; ni < 2; ++ni) {
            int m = m0 + wr * 64 + mi * 16 + l16;
            int n = n0 + wc * 32 + ni * 16 + quad * 4;
            *(f32x4*)&Cout[(size_t)m * D_ + n] = acc[mi][ni];
        }
}

// ---------------------------------------------------------------- flash attention
// (round-10 verbatim: round-7 structure + v_max3 trees — best verified, attn ~53 µs)
__device__ __constant__ unsigned char ITEM_QT[24] = {
    8,9,10,11,12,13,14,15, 7,15, 6,14, 5,13, 4,12, 3,11, 2,10, 1,9, 0,8};
__device__ __constant__ unsigned char ITEM_KIND[24] = {  // 0=full 1=chunk0 2=chunk1
    1,1,1,1,1,1,1,1, 0,2, 0,2, 0,2, 0,2, 0,2, 0,2, 0,2, 0,2};

#define LDP 136

struct VStage { bf16x8 v0, v1; };

__global__ __launch_bounds__(512, 4) void attn_kernel(const bf16* __restrict__ Q,
                                                      const bf16* __restrict__ K,
                                                      const bf16* __restrict__ Vt,
                                                      bf16* __restrict__ O,
                                                      float* __restrict__ Opart,
                                                      float2* __restrict__ ML) {
    __shared__ bf16 Kh[2][2][128 * 32];  // [buf][k-half][key*32 + kcol] linear
    __shared__ bf16 Vs[64 * LDP];        // [dim][permuted key col]

    const int bh = blockIdx.x;                 // 0..31
    const int item = blockIdx.y;               // 0..23 (descending size)
    const int qt = ITEM_QT[item];              // 128-row q tile
    const int kind = ITEM_KIND[item];
    const int h = bh & (H_ - 1), b = bh >> 4;
    const int tid = threadIdx.x;
    const int wave = tid >> 6, lane = tid & 63;
    const int quad = lane >> 4, l16 = lane & 15;

    const bf16* Qb = Q + (size_t)bh * T_ * HD;
    const bf16* Kb = K + (size_t)bh * T_ * HD;
    const bf16* Vb = Vt + (size_t)bh * HD * T_;   // [hd][T]

    const float slope2 = exp2f(-0.5f * (float)(h + 1)) * 1.44269504f;  // log2-domain slope

    bf16x8 qf[2];
    {
        const bf16* qrow = Qb + (size_t)(qt * 128 + wave * 16 + l16) * HD + quad * 8;
        qf[0] = *(const bf16x8*)(qrow);
        qf[1] = *(const bf16x8*)(qrow + 32);
    }

    // K staging via gl2lds: thread t covers key = t>>2, kcol = (t&3)*8 of each half.
    auto stageK = [&](int buf, int t) {
        const bf16* kg = Kb + ((size_t)t * 128 + (tid >> 2)) * HD + ((tid & 3) << 3);
        GL2LDS16(kg,      &Kh[buf][0][tid * 8]);
        GL2LDS16(kg + 32, &Kh[buf][1][tid * 8]);
    };

    // V staging (reg round-trip for the permuted-column layout)
    const int slot0 = tid, slot1 = 512 + tid;
    const int rv0 = slot0 >> 4, c0 = slot0 & 15;
    const int rv1 = slot1 >> 4, c1 = slot1 & 15;
    const int vs0 = rv0 * LDP + (c0 & 1) * 64 + (c0 >> 1) * 4;
    const int vs1 = rv1 * LDP + (c1 & 1) * 64 + (c1 >> 1) * 4;

    auto loadV = [&](int t, VStage& st) {
        const bf16* vb = Vb + t * 128;
        st.v0 = *(const bf16x8*)(vb + (size_t)rv0 * T_ + c0 * 8);
        st.v1 = *(const bf16x8*)(vb + (size_t)rv1 * T_ + c1 * 8);
    };
    auto storeV = [&](const VStage& st) {
        *(bf16x4*)&Vs[vs0]      = lo4(st.v0);
        *(bf16x4*)&Vs[vs0 + 32] = hi4(st.v0);
        *(bf16x4*)&Vs[vs1]      = lo4(st.v1);
        *(bf16x4*)&Vs[vs1 + 32] = hi4(st.v1);
    };

    f32x4 acc[4];                    // O^T: d = df*16+quad*4+r, query = l16
    for (int df = 0; df < 4; ++df) acc[df] = (f32x4){0.f, 0.f, 0.f, 0.f};
    float m_run = -INFINITY, l_lane = 0.f;

    const int qglob = qt * 128 + wave * 16 + l16;
    const int nkt = qt + 1;                        // 128-key tiles for full row
    const int kt0 = (kind == 2) ? 8 : 0;
    const int kt1 = (kind == 1) ? 8 : nkt;

    auto compute = [&](int kt, int buf, bool last) {
        f32x4 s[8];
#pragma unroll
        for (int nf = 0; nf < 8; ++nf) {
            bf16x8 kf0 = *(const bf16x8*)&Kh[buf][0][(nf * 16 + l16) * 32 + quad * 8];
            bf16x8 kf1 = *(const bf16x8*)&Kh[buf][1][(nf * 16 + l16) * 32 + quad * 8];
            f32x4 zz = (f32x4){0.f, 0.f, 0.f, 0.f};
            __builtin_amdgcn_s_setprio(1);
            zz = __builtin_amdgcn_mfma_f32_16x16x32_bf16(kf0, qf[0], zz, 0, 0, 0);
            zz = __builtin_amdgcn_mfma_f32_16x16x32_bf16(kf1, qf[1], zz, 0, 0, 0);
            __builtin_amdgcn_s_setprio(0);
            s[nf] = zz;
        }

        // Q pre-scaled -> s already in log2 domain; add alibi, mask last tile
        const float j0f = (float)(kt * 128 + quad * 4 - (T_ - 1));
#pragma unroll
        for (int nf = 0; nf < 8; ++nf)
#pragma unroll
            for (int r = 0; r < 4; ++r)
                s[nf][r] += slope2 * (j0f + (float)(nf * 16 + r));
        if (last) {
            const int jb = kt * 128 + quad * 4;
#pragma unroll
            for (int nf = 0; nf < 8; ++nf)
#pragma unroll
                for (int r = 0; r < 4; ++r)
                    if (jb + nf * 16 + r > qglob) s[nf][r] = -INFINITY;
        }

        // max reduction, v_max3-fusable nesting (T17), then cross-quad
        float a[8];
#pragma unroll
        for (int nf = 0; nf < 8; ++nf)
            a[nf] = fmaxf(fmaxf(fmaxf(s[nf][0], s[nf][1]), s[nf][2]), s[nf][3]);
        float m012 = fmaxf(fmaxf(a[0], a[1]), a[2]);
        float m345 = fmaxf(fmaxf(a[3], a[4]), a[5]);
        float m67  = fmaxf(a[6], a[7]);
        float mx = fmaxf(fmaxf(m012, m345), m67);
        mx = fmaxf(mx, __shfl_xor(mx, 16, 64));
        mx = fmaxf(mx, __shfl_xor(mx, 32, 64));

        // defer-max (T13): rescale only when tile max grew past threshold (log2 domain)
        if (!__all(mx - m_run <= 8.f)) {
            const float mnew = fmaxf(m_run, mx);
            const float alpha = exp2f(m_run - mnew);
            l_lane *= alpha;
#pragma unroll
            for (int df = 0; df < 4; ++df) acc[df] *= alpha;
            m_run = mnew;
        }

        float rs0 = 0.f, rs1 = 0.f;
        bf16x4 pf[8];
#pragma unroll
        for (int nf = 0; nf < 8; ++nf) {
            float p0 = exp2f(s[nf][0] - m_run);
            float p1 = exp2f(s[nf][1] - m_run);
            float p2 = exp2f(s[nf][2] - m_run);
            float p3 = exp2f(s[nf][3] - m_run);
            if (nf & 1) rs1 += (p0 + p1) + (p2 + p3);
            else        rs0 += (p0 + p1) + (p2 + p3);
            pf[nf] = (bf16x4){(bf16)p0, (bf16)p1, (bf16)p2, (bf16)p3};
        }
        l_lane += rs0 + rs1;          // cross-quad l reduction deferred to epilogue

        // PV: permuted V cols -> b128 reads (2-way on writes only = free)
#pragma unroll
        for (int j = 0; j < 4; ++j) {
            bf16x8 w[4];
#pragma unroll
            for (int df = 0; df < 4; ++df)
                w[df] = *(const bf16x8*)&Vs[(df * 16 + l16) * LDP + quad * 32 + j * 8];
            __builtin_amdgcn_s_setprio(1);
#pragma unroll
            for (int df = 0; df < 4; ++df) {
                acc[df] = mfma16x16x16(lo4(w[df]), pf[2 * j],     acc[df]);
                acc[df] = mfma16x16x16(hi4(w[df]), pf[2 * j + 1], acc[df]);
            }
            __builtin_amdgcn_s_setprio(0);
        }
    };

    // Pipeline: K double-buffered in LDS (gl2lds), V single-buffered with reg prefetch.
    // Prefetches for kt+1 issued AFTER barrier (B), drained at the NEXT (B).
    VStage sA, sB;
    stageK(0, kt0);
    loadV(kt0, sA);
    int kt = kt0;
    for (;;) {
        __syncthreads();               // (A) prior compute's Vs reads done
        storeV(sA);                    // waits on V(kt) regs (covered by prior compute)
        __syncthreads();               // (B) drains K(kt) gl2lds; V writes visible
        if (kt + 1 < kt1) { stageK(1, kt + 1); loadV(kt + 1, sB); }
        compute(kt, 0, kt == nkt - 1);
        if (++kt >= kt1) break;
        __syncthreads();
        storeV(sB);
        __syncthreads();
        if (kt + 1 < kt1) { stageK(0, kt + 1); loadV(kt + 1, sA); }
        compute(kt, 1, kt == nkt - 1);
        if (++kt >= kt1) break;
    }

    float l_run = l_lane;
    l_run += __shfl_xor(l_run, 16, 64);
    l_run += __shfl_xor(l_run, 32, 64);

    if (kind == 0) {
        const float inv = 1.0f / l_run;
        for (int df = 0; df < 4; ++df) {
            bf16 o4[4];
            for (int r = 0; r < 4; ++r) o4[r] = (bf16)(acc[df][r] * inv);
            *(uint2*)&O[(((size_t)b * T_ + qglob) * H_ + h) * HD + df * 16 + quad * 4] =
                *(const uint2*)o4;
        }
    } else {
        const int pidx = (bh * 8 + (qt - 8)) * 2 + (kind == 2 ? 1 : 0);
        const int ql = wave * 16 + l16;        // 0..127
        float* dst = Opart + (size_t)pidx * 8192 + ql * 64;
        for (int df = 0; df < 4; ++df)
            *(f32x4*)&dst[df * 16 + quad * 4] = acc[df];
        if (quad == 0) ML[pidx * 128 + ql] = make_float2(m_run, l_run);
    }
}

// ---------------------------------------------------------------- partial merge
// grid (8, 32) x 512 thr: q = tid>>2 (0..127), d-chunk = (tid&3)*16.
__global__ __launch_bounds__(512) void attn_merge(const float* __restrict__ Opart,
                                                  const float2* __restrict__ ML,
                                                  bf16* __restrict__ O) {
    const int qt = 8 + blockIdx.x, bh = blockIdx.y;
    const int h = bh & (H_ - 1), b = bh >> 4;
    const int tid = threadIdx.x;
    const int q = tid >> 2, dc = (tid & 3) << 4;
    const int p0 = (bh * 8 + blockIdx.x) * 2, p1 = p0 + 1;

    const float2 ml0 = ML[p0 * 128 + q], ml1 = ML[p1 * 128 + q];
    const float M = fmaxf(ml0.x, ml1.x);
    const float e0 = exp2f(ml0.x - M), e1 = exp2f(ml1.x - M);
    const float inv = 1.0f / (e0 * ml0.y + e1 * ml1.y);

    const float* a = Opart + (size_t)p0 * 8192 + q * 64 + dc;
    const float* c = Opart + (size_t)p1 * 8192 + q * 64 + dc;
    bf16 o16[16];
    for (int j = 0; j < 4; ++j) {
        f32x4 va = *(const f32x4*)(a + j * 4);
        f32x4 vc = *(const f32x4*)(c + j * 4);
        for (int r = 0; r < 4; ++r)
            o16[j * 4 + r] = (bf16)((va[r] * e0 + vc[r] * e1) * inv);
    }
    const int t = qt * 128 + q;
    bf16* dst = O + (((size_t)b * T_ + t) * H_ + h) * HD + dc;
    *(bf16x8*)dst = *(const bf16x8*)o16;
    *(bf16x8*)(dst + 8) = *(const bf16x8*)(o16 + 8);
}

// ---------------------------------------------------------------- launch
extern "C" void kernel_launch(void* const* d_in, const int* in_sizes, int n_in,
                              void* d_out, int out_size, void* d_ws, size_t ws_size,
                              hipStream_t stream) {
    const float* x  = (const float*)d_in[0];
    const float* Wq = (const float*)d_in[1];
    const float* Wk = (const float*)d_in[2];
    const float* Wv = (const float*)d_in[3];
    const float* Wo = (const float*)d_in[4];
    float* out = (float*)d_out;

    const size_t M = (size_t)B_ * T_;        // 4096
    const size_t XE = M * D_;                // 4 Mi elems
    const size_t WE = (size_t)D_ * D_;       // 1 Mi elems

    char* ws = (char*)d_ws;
    size_t off = 0;
    auto carve = [&](size_t bytes) {
        void* p = ws + off;
        off += (bytes + 255) & ~(size_t)255;
        return p;
    };
    bf16* xb  = (bf16*)carve(XE * 2);        // x bf16; reused as attn_out later
    bf16* Wt  = (bf16*)carve(4 * WE * 2);    // Wq,Wk,Wv,Wo transposed [N][K]
    bf16* QKV = (bf16*)carve(3 * XE * 2);    // Q,K [B,H,T,hd]; V [B,H,hd,T]
    float*  Opart = (float*)carve(32 * 8 * 2 * 8192 * sizeof(float));    // 16.8 MB
    float2* MLbuf = (float2*)carve(32 * 8 * 2 * 128 * sizeof(float2));   // 0.5 MB
    bf16* attn = xb;  // safe: xb fully consumed by QKV gemm before attn_kernel runs

    prep_inputs<<<dim3(16, 16, 20), 256, 0, stream>>>(x, Wq, Wk, Wv, Wo, xb, Wt);

    gemm_qkv<<<512, 256, 0, stream>>>(xb, Wt, QKV);
    attn_kernel<<<dim3(32, 24), 512, 0, stream>>>(QKV, QKV + XE, QKV + 2 * XE,
                                                  attn, Opart, MLbuf);
    attn_merge<<<dim3(8, 32), 512, 0, stream>>>(Opart, MLbuf, attn);
    gemm_out<<<512, 256, 0, stream>>>(attn, Wt + 3 * WE, out);
}